// Round 3
// baseline (177.657 us; speedup 1.0000x reference)
//
#include <hip/hip_runtime.h>
#include <hip/hip_bf16.h>

// Problem constants (fixed by setup_inputs)
#define B_SZ 8
#define H_SZ 32     // image rows
#define W_SZ 64     // image cols
#define N_SZ 2048   // H*W
#define C_SZ 512
#define NH 8        // heads
#define HD 64       // head dim
// window 7x11 -> +-3 rows, +-5 cols

using u16 = unsigned short;
typedef __attribute__((ext_vector_type(8))) short s16x8;
typedef __attribute__((ext_vector_type(4))) float f32x4;

__device__ __forceinline__ float bf2f(u16 u) {
    union { unsigned int i; float f; } c; c.i = ((unsigned int)u) << 16; return c.f;
}
__device__ __forceinline__ u16 f2bf(float f) {
    union { float f; unsigned int i; } c; c.f = f;
    unsigned int r = c.i + 0x7fffu + ((c.i >> 16) & 1u);  // RNE
    return (u16)(r >> 16);
}

// async global->LDS, 16B per lane; LDS dest must be wave-uniform base + lane*16
#define GLL16(gp, lp) __builtin_amdgcn_global_load_lds( \
    (const __attribute__((address_space(1))) unsigned int*)(gp), \
    (__attribute__((address_space(3))) unsigned int*)(lp), 16, 0, 0)

// XOR-swizzled 64-elem rows (8 chunks of 8 bf16): chunk c of row r at slot c^(r&7)
__device__ __forceinline__ int lds_off(int row, int chunk) {
    return (row * 8 + (chunk ^ (row & 7))) * 8;   // element offset
}
// XOR-swizzled 32-elem rows (4 chunks of 8 bf16): chunk c of row r at slot c^(r&3)
// ds_read_b128 over 16 rows x fixed c: start banks {4*(c^(r&3)) + 16*(r&1)} ->
// 8 distinct 16B slots, 2 lanes each = 2-way (free).
__device__ __forceinline__ int lds_off32(int row, int chunk) {
    return (row * 4 + (chunk ^ (row & 3))) * 8;   // element offset
}

// ---------------- fused fp32 -> bf16 convert (x, qkv_w [q-rows scaled], proj_w) ----
#define NX4 2097152   // x float4 count (16384*512/4)
#define NQ4 196608    // qkv_w float4 count
#define NP4 65536     // proj_w float4 count
__global__ __launch_bounds__(256)
void conv_all(const float* __restrict__ x, const float* __restrict__ qw,
              const float* __restrict__ pw, u16* __restrict__ xb,
              u16* __restrict__ qwb, u16* __restrict__ pwb)
{
    const int i = blockIdx.x * 256 + threadIdx.x;
    const float* src; u16* dst; int idx; float sc = 1.0f;
    if (i < NX4)             { src = x;  dst = xb;  idx = i; }
    else if (i < NX4 + NQ4)  { src = qw; dst = qwb; idx = i - NX4;
                               if (idx < 65536) sc = 0.125f; }  // q-rows: fold 64^-0.5
    else                     { src = pw; dst = pwb; idx = i - NX4 - NQ4; }
    const float4 v = ((const float4*)src)[idx];
    ushort4 o = { f2bf(v.x * sc), f2bf(v.y * sc), f2bf(v.z * sc), f2bf(v.w * sc) };
    ((ushort4*)dst)[idx] = o;
}

// ---------------- triple-buffered MFMA GEMM: C[m,n] = sum_k A[m,k]*Bw[n,k] ------
// 256x128 tile, BK=32, 16 K-tiles, 8 waves (2M x 4N, each 128x32 out).
// THREE LDS buffers (72 KB): staging runs TWO K-tiles ahead; per tile top a
// counted s_waitcnt vmcnt(3) waits only the 2-tiles-old loads (never drains the
// queue), then ONE barrier.  Two 8-MFMA phases; phase-1 ds_reads are free to
// interleave with phase-0 MFMAs (no sched wall between).  launch_bounds(512,4)
// forces <=128 VGPR so 2 blocks/CU can co-reside (LDS 72KB*2 <= 160KB).
// MODE 0: scatter q/k ([bh][n][d]) and v transposed ([bh][d][n])
// MODE 1: +bias -> fp32 outp
template<int MODE, int NB>
__global__ __launch_bounds__(512, 4)
void gemm3(const u16* __restrict__ A, const u16* __restrict__ Bw,
           const float* __restrict__ bias,
           u16* __restrict__ q_ws, u16* __restrict__ k_ws, u16* __restrict__ v_ws,
           float* __restrict__ outp)
{
    __shared__ u16 As[3][256 * 32];   // 48 KB
    __shared__ u16 Bs[3][128 * 32];   // 24 KB
    const int t = threadIdx.x;
    // bijective XCD swizzle (gridDim.x % 8 == 0), n-fast within each XCD chunk
    const int chunk = gridDim.x >> 3;
    const int wg = (blockIdx.x & 7) * chunk + (blockIdx.x >> 3);
    const int m0 = (wg / NB) * 256;
    const int n0 = (wg % NB) * 128;
    const int wave = t >> 6, lane = t & 63;
    const int wm = (wave >> 2) * 128;         // 0,128
    const int wn = (wave & 3) * 32;           // 0,32,64,96
    const int l16 = lane & 15, quad = lane >> 4;
    const int srow = t >> 2;                  // staging row 0..127
    const int sch  = (t & 3) ^ (srow & 3);    // swizzled chunk for this slot

    const u16* Ab = A  + (size_t)(m0 + srow) * C_SZ + sch * 8;
    const u16* Bb = Bw + (size_t)(n0 + srow) * C_SZ + sch * 8;

    f32x4 acc[8][2] = {};

    // prologue: stage K-tiles 0,1 (3 GLL each: A rows 0-127, A rows 128-255, B)
    #pragma unroll
    for (int tb = 0; tb < 2; ++tb) {
        GLL16(Ab + tb * 32,                       &As[tb][t * 8]);
        GLL16(Ab + (size_t)128 * C_SZ + tb * 32,  &As[tb][4096 + t * 8]);
        GLL16(Bb + tb * 32,                       &Bs[tb][t * 8]);
    }

    #pragma unroll
    for (int tt = 0; tt < 16; ++tt) {
        const int cb = tt % 3;
        // wait ONLY the 2-tiles-old staging (issued at top of iter tt-2):
        // outstanding here = tile tt (3) + tile tt+1 (3); keep tt+1 in flight.
        if (tt < 15) asm volatile("s_waitcnt vmcnt(3)" ::: "memory");
        else         asm volatile("s_waitcnt vmcnt(0)" ::: "memory");
        __builtin_amdgcn_s_barrier();     // all waves' tile-tt staging visible;
                                          // also: all tile-(tt-1) reads complete
        __builtin_amdgcn_sched_barrier(0);

        // stage tile tt+2 into the buffer freed by tile tt-1
        if (tt < 14) {
            const int nb = (tt + 2) % 3;
            const int k0 = (tt + 2) * 32;
            GLL16(Ab + k0,                         &As[nb][t * 8]);
            GLL16(Ab + (size_t)128 * C_SZ + k0,    &As[nb][4096 + t * 8]);
            GLL16(Bb + k0,                         &Bs[nb][t * 8]);
        }

        // ---- phase 0: A subtiles 0-3 + both B subtiles -> 8 MFMA ----
        s16x8 af0[4], bf[2];
        #pragma unroll
        for (int i = 0; i < 4; ++i)
            af0[i] = *(const s16x8*)&As[cb][lds_off32(wm + 16 * i + l16, quad)];
        #pragma unroll
        for (int j = 0; j < 2; ++j)
            bf[j] = *(const s16x8*)&Bs[cb][lds_off32(wn + 16 * j + l16, quad)];
        asm volatile("s_waitcnt lgkmcnt(0)" ::: "memory");
        __builtin_amdgcn_sched_barrier(0);
        __builtin_amdgcn_s_setprio(1);
        #pragma unroll
        for (int i = 0; i < 4; ++i)
            #pragma unroll
            for (int j = 0; j < 2; ++j)
                acc[i][j] = __builtin_amdgcn_mfma_f32_16x16x32_bf16(af0[i], bf[j], acc[i][j], 0, 0, 0);
        __builtin_amdgcn_s_setprio(0);

        // ---- phase 1: A subtiles 4-7 (reads overlap phase-0 MFMA drain) ----
        s16x8 af1[4];
        #pragma unroll
        for (int i = 0; i < 4; ++i)
            af1[i] = *(const s16x8*)&As[cb][lds_off32(wm + 64 + 16 * i + l16, quad)];
        asm volatile("s_waitcnt lgkmcnt(0)" ::: "memory");
        __builtin_amdgcn_sched_barrier(0);
        __builtin_amdgcn_s_setprio(1);
        #pragma unroll
        for (int i = 0; i < 4; ++i)
            #pragma unroll
            for (int j = 0; j < 2; ++j)
                acc[4 + i][j] = __builtin_amdgcn_mfma_f32_16x16x32_bf16(af1[i], bf[j], acc[4 + i][j], 0, 0, 0);
        __builtin_amdgcn_s_setprio(0);
    }

    // epilogue: C row = m0+wm+16i+quad*4+r, col = n0+wn+16j+l16
    if (MODE == 0) {
        const int bb  = m0 >> 11;                      // batch (block-uniform)
        const int nnb = (m0 & 2047) + wm + (quad << 2);
        if (n0 >= 1024) {
            // pure V block: store transposed [bh][d][n], pack 4 rows -> ushort4
            #pragma unroll
            for (int j = 0; j < 2; ++j) {
                const int c  = n0 - 1024 + wn + 16 * j + l16;   // v col 0..511
                const int h  = c >> 6, dd = c & 63;
                u16* vp = v_ws + (((size_t)bb * NH + h) * HD + dd) * N_SZ + nnb;
                #pragma unroll
                for (int i = 0; i < 8; ++i) {
                    ushort4 st = { f2bf(acc[i][j][0]), f2bf(acc[i][j][1]),
                                   f2bf(acc[i][j][2]), f2bf(acc[i][j][3]) };
                    *(ushort4*)(vp + 16 * i) = st;
                }
            }
        } else {
            u16* T = (n0 < 512) ? q_ws : k_ws;         // block-uniform target
            const int nq = n0 & 511;
            #pragma unroll
            for (int j = 0; j < 2; ++j) {
                const int gn = nq + wn + 16 * j + l16;
                const int h  = gn >> 6, dd = gn & 63;
                u16* tp = T + (((size_t)bb * NH + h) * N_SZ + nnb) * HD + dd;
                #pragma unroll
                for (int i = 0; i < 8; ++i)
                    #pragma unroll
                    for (int r = 0; r < 4; ++r)
                        tp[(size_t)(16 * i + r) * HD] = f2bf(acc[i][j][r]);
            }
        }
    } else {
        #pragma unroll
        for (int j = 0; j < 2; ++j) {
            const int gn = n0 + wn + 16 * j + l16;
            const float bv = bias[gn];
            #pragma unroll
            for (int i = 0; i < 8; ++i)
                #pragma unroll
                for (int r = 0; r < 4; ++r)
                    outp[(size_t)(m0 + wm + 16 * i + (quad << 2) + r) * C_SZ + gn]
                        = acc[i][j][r] + bv;
        }
    }
}

// ---------------- MFMA local attention: 2 image rows / block ----------------
// block = (bh, row-pair p): queries = rows 2p,2p+1 (128 q).  Wave w handles the
// 16-query span [16w,16w+16) in BOTH rows, key window [kb,kb+32),
// kb = clamp(16w-8,0,32).  K/V rows 2p-3 .. 2p+4 staged one at a time; V frags
// shared across the two row-subtiles.  Q staged through the K/V LDS then kept in
// registers (26 KB LDS total -> 6 blocks/CU capacity).
__global__ __launch_bounds__(256)
void attn_mfma(const u16* __restrict__ q_ws, const u16* __restrict__ k_ws,
               const u16* __restrict__ vt_ws, u16* __restrict__ o_ws)
{
    __shared__ u16 KV[2][64 * 64];   // [0]=K row, [1]=Vt row; Q staging at start
    __shared__ u16 Ps[4][16 * 40];   // per-wave P, [q16][key32], stride 40 elems

    const int t = threadIdx.x, wave = t >> 6, lane = t & 63;
    const int l16 = lane & 15, quad = lane >> 4;
    const int u  = blockIdx.x;
    const int p  = u & 15;           // row pair
    const int bh = u >> 4;
    const int r0 = 2 * p, r1 = 2 * p + 1;
    const size_t base = (size_t)bh * (N_SZ * HD);
    const int srow = t >> 3;
    const int sch  = (t & 7) ^ (srow & 7);

    // stage Q rows r0,r1 (128x64 = 16 KB) into KV, swizzled; extract frags
    const u16* qg = q_ws + base + (size_t)r0 * (64 * HD);
    u16* Qst = &KV[0][0];
    #pragma unroll
    for (int g = 0; g < 4; ++g)
        GLL16(qg + (size_t)(srow + 32 * g) * 64 + sch * 8, Qst + g * 2048 + t * 8);
    __syncthreads();

    s16x8 aQ[2][2];
    #pragma unroll
    for (int s = 0; s < 2; ++s) {
        const int Rq = 64 * s + 16 * wave + l16;
        aQ[s][0] = *(const s16x8*)&Qst[lds_off(Rq, quad)];
        aQ[s][1] = *(const s16x8*)&Qst[lds_off(Rq, 4 + quad)];
    }

    const int kb = min(max(16 * wave - 8, 0), 32);   // 0, 8, 24, 32

    f32x4 accO[2][4] = {};
    float lp[2][4] = {};

    const int hlo = (r0 - 3 < 0) ? 0 : r0 - 3;
    const int hhi = (r1 + 3 > H_SZ - 1) ? H_SZ - 1 : r1 + 3;

    for (int hh = hlo; hh <= hhi; ++hh) {
        __syncthreads();   // previous iter's reads (and Q extract) done
        const u16* kg = k_ws + base + (size_t)hh * (64 * HD);
        GLL16(kg + (size_t)srow        * 64 + sch * 8, &KV[0][t * 8]);
        GLL16(kg + (size_t)(srow + 32) * 64 + sch * 8, &KV[0][2048 + t * 8]);
        const u16* vg = vt_ws + base + (size_t)hh * 64;
        GLL16(vg + (size_t)srow        * N_SZ + sch * 8, &KV[1][t * 8]);
        GLL16(vg + (size_t)(srow + 32) * N_SZ + sch * 8, &KV[1][2048 + t * 8]);
        __syncthreads();

        // K/V frags for this wave's 32-key window
        s16x8 bK[2][2];
        #pragma unroll
        for (int j = 0; j < 2; ++j) {
            const int Rk = kb + 16 * j + l16;
            bK[j][0] = *(const s16x8*)&KV[0][lds_off(Rk, quad)];
            bK[j][1] = *(const s16x8*)&KV[0][lds_off(Rk, 4 + quad)];
        }
        s16x8 vf[4];
        #pragma unroll
        for (int j = 0; j < 4; ++j)
            vf[j] = *(const s16x8*)&KV[1][lds_off(16 * j + l16, (kb >> 3) + quad)];

        #pragma unroll
        for (int s = 0; s < 2; ++s) {
            const int dh = hh - (r0 + s);
            if (dh * dh > 9) continue;     // wave-uniform: row out of +-3 range
            f32x4 z[2] = {{0.f,0.f,0.f,0.f},{0.f,0.f,0.f,0.f}};
            #pragma unroll
            for (int j = 0; j < 2; ++j) {
                z[j] = __builtin_amdgcn_mfma_f32_16x16x32_bf16(aQ[s][0], bK[j][0], z[j], 0, 0, 0);
                z[j] = __builtin_amdgcn_mfma_f32_16x16x32_bf16(aQ[s][1], bK[j][1], z[j], 0, 0, 0);
            }
            #pragma unroll
            for (int j = 0; j < 2; ++j) {
                const int ww = kb + 16 * j + l16;   // key w-coord
                #pragma unroll
                for (int r = 0; r < 4; ++r) {
                    const int dw = ww - (16 * wave + quad * 4 + r);
                    const float pv = (dw * dw <= 25) ? __expf(z[j][r]) : 0.f;
                    const u16 pb = f2bf(pv);
                    lp[s][r] += bf2f(pb);
                    Ps[wave][(quad * 4 + r) * 40 + 16 * j + l16] = pb;
                }
            }
            s16x8 aP = *(const s16x8*)&Ps[wave][l16 * 40 + quad * 8];
            #pragma unroll
            for (int j = 0; j < 4; ++j)
                accO[s][j] = __builtin_amdgcn_mfma_f32_16x16x32_bf16(aP, vf[j], accO[s][j], 0, 0, 0);
        }
    }

    // reduce l across the 16 lanes sharing a quad-row (disjoint key subsets)
    #pragma unroll
    for (int s = 0; s < 2; ++s)
        #pragma unroll
        for (int r = 0; r < 4; ++r) {
            lp[s][r] += __shfl_xor(lp[s][r], 1);
            lp[s][r] += __shfl_xor(lp[s][r], 2);
            lp[s][r] += __shfl_xor(lp[s][r], 4);
            lp[s][r] += __shfl_xor(lp[s][r], 8);
        }

    // write O in (B, N, C) layout for the proj GEMM
    const int bb = bh >> 3, h = bh & 7;
    #pragma unroll
    for (int s = 0; s < 2; ++s)
        #pragma unroll
        for (int j = 0; j < 4; ++j)
            #pragma unroll
            for (int r = 0; r < 4; ++r) {
                const int row = (r0 + s) * 64 + 16 * wave + quad * 4 + r;
                o_ws[((size_t)bb * N_SZ + row) * C_SZ + h * 64 + 16 * j + l16]
                    = f2bf(accO[s][j][r] / lp[s][r]);
            }
}

extern "C" void kernel_launch(void* const* d_in, const int* in_sizes, int n_in,
                              void* d_out, int out_size, void* d_ws, size_t ws_size,
                              hipStream_t stream)
{
    const float* x      = (const float*)d_in[0];
    const float* qkv_w  = (const float*)d_in[1];
    const float* proj_w = (const float*)d_in[2];
    const float* proj_b = (const float*)d_in[3];
    float* outp = (float*)d_out;

    const size_t seg = (size_t)B_SZ * NH * N_SZ * HD;  // 8388608 elems
    u16* q_ws = (u16*)d_ws;
    u16* k_ws = q_ws + seg;
    u16* v_ws = k_ws + seg;      // transposed layout [bh][d][n]
    u16* o_ws = v_ws + seg;
    u16* xb   = o_ws + seg;                       // x as bf16 (8.4M elems)
    u16* qwb  = xb + (size_t)16384 * 512;         // qkv_w bf16 (786432)
    u16* pwb  = qwb + (size_t)1536 * 512;         // proj_w bf16 (262144)

    // one fused convert: (NX4+NQ4+NP4)/256 = 9216 blocks
    conv_all<<<9216, 256, 0, stream>>>(x, qkv_w, proj_w, xb, qwb, pwb);

    // QKV GEMM: M=16384, N=1536, K=512 -> 64 x 12 = 768 blocks of 256x128
    gemm3<0, 12><<<768, 512, 0, stream>>>(xb, qwb, nullptr,
                                          q_ws, k_ws, v_ws, nullptr);
    // local attention, one block per (b,h,row-pair)
    attn_mfma<<<B_SZ * NH * (H_SZ / 2), 256, 0, stream>>>(q_ws, k_ws, v_ws, o_ws);
    // proj GEMM: M=16384, N=512, K=512 (+bias, fp32 out) -> 64 x 4 = 256 blocks
    gemm3<1, 4><<<256, 512, 0, stream>>>(o_ws, pwb, proj_b,
                                         nullptr, nullptr, nullptr, outp);
}

// Round 4
// 173.858 us; speedup vs baseline: 1.0219x; 1.0219x over previous
//
#include <hip/hip_runtime.h>
#include <hip/hip_bf16.h>

// Problem constants (fixed by setup_inputs)
#define B_SZ 8
#define H_SZ 32     // image rows
#define W_SZ 64     // image cols
#define N_SZ 2048   // H*W
#define C_SZ 512
#define NH 8        // heads
#define HD 64       // head dim
// window 7x11 -> +-3 rows, +-5 cols

using u16 = unsigned short;
typedef __attribute__((ext_vector_type(8))) short s16x8;
typedef __attribute__((ext_vector_type(4))) float f32x4;

__device__ __forceinline__ float bf2f(u16 u) {
    union { unsigned int i; float f; } c; c.i = ((unsigned int)u) << 16; return c.f;
}
__device__ __forceinline__ u16 f2bf(float f) {
    union { float f; unsigned int i; } c; c.f = f;
    unsigned int r = c.i + 0x7fffu + ((c.i >> 16) & 1u);  // RNE
    return (u16)(r >> 16);
}

// async global->LDS, 16B per lane; LDS dest must be wave-uniform base + lane*16
#define GLL16(gp, lp) __builtin_amdgcn_global_load_lds( \
    (const __attribute__((address_space(1))) unsigned int*)(gp), \
    (__attribute__((address_space(3))) unsigned int*)(lp), 16, 0, 0)

// XOR-swizzled 64-elem rows: row = 8 chunks of 8 bf16 (16B); data chunk c of row r
// lives at slot position c ^ (r&7).  Conflict-free ds_read_b128 across l16 lanes.
// (proven 0-conflict in rounds 0-2; the 32-wide variant conflicted -> reverted)
__device__ __forceinline__ int lds_off(int row, int chunk) {
    return (row * 8 + (chunk ^ (row & 7))) * 8;   // element offset
}

// ---------------- fused fp32 -> bf16 convert (x, qkv_w [q-rows scaled], proj_w) ----
#define NX4 2097152   // x float4 count (16384*512/4)
#define NQ4 196608    // qkv_w float4 count
#define NP4 65536     // proj_w float4 count
__global__ __launch_bounds__(256)
void conv_all(const float* __restrict__ x, const float* __restrict__ qw,
              const float* __restrict__ pw, u16* __restrict__ xb,
              u16* __restrict__ qwb, u16* __restrict__ pwb)
{
    const int i = blockIdx.x * 256 + threadIdx.x;
    const float* src; u16* dst; int idx; float sc = 1.0f;
    if (i < NX4)             { src = x;  dst = xb;  idx = i; }
    else if (i < NX4 + NQ4)  { src = qw; dst = qwb; idx = i - NX4;
                               if (idx < 65536) sc = 0.125f; }  // q-rows: fold 64^-0.5
    else                     { src = pw; dst = pwb; idx = i - NX4 - NQ4; }
    const float4 v = ((const float4*)src)[idx];
    ushort4 o = { f2bf(v.x * sc), f2bf(v.y * sc), f2bf(v.z * sc), f2bf(v.w * sc) };
    ((ushort4*)dst)[idx] = o;
}

// ------- phase-split MFMA GEMM: C[m,n] = sum_k A[m,k]*Bw[n,k] (bf16, K-contig) ----
// 128x256 tile, BK=64, 8 K-tiles, 8 waves (2M x 4N, per-wave 64x64 out).
// THREE LDS buffers (144 KB), staging runs TWO tiles ahead; per tile:
//   top:  s_waitcnt vmcnt(6)  (waits only this tile's 6 loads; next tile's 6
//         stay in flight -- never drains until the last tile) + ONE s_barrier.
//   phase 0: 12 ds_read_b128 (m-frags 0-1 + all B) + 3 GLL (tile t+2)
//            -> 16 MFMA  (compiler emits fine-grained lgkmcnt; no asm wall)
//   phase 1:  4 ds_read_b128 (m-frags 2-3)        + 3 GLL (tile t+2)
//            -> 16 MFMA
// Buffer safety: tile t+2 writes buf (t-1)%3; every wave's tile-(t-1) reads
// completed before it passed the top-of-t barrier (reads precede its MFMA issue).
// MODE 0: scatter q/k ([bh][n][d]) and v transposed ([bh][d][n]); MODE 1: +bias fp32
template<int MODE, int NB>
__global__ __launch_bounds__(512)
void gemm8(const u16* __restrict__ A, const u16* __restrict__ Bw,
           const float* __restrict__ bias,
           u16* __restrict__ q_ws, u16* __restrict__ k_ws, u16* __restrict__ v_ws,
           float* __restrict__ outp)
{
    __shared__ u16 As[3][128 * 64];   // 48 KB
    __shared__ u16 Bs[3][256 * 64];   // 96 KB   (total 144 KB -> 1 block/CU)
    const int t = threadIdx.x;
    // bijective XCD swizzle (gridDim.x % 8 == 0), n-fast within each XCD chunk
    const int chunk = gridDim.x >> 3;
    const int wg = (blockIdx.x & 7) * chunk + (blockIdx.x >> 3);
    const int m0 = (wg / NB) * 128;
    const int n0 = (wg % NB) * 256;
    const int wave = t >> 6, lane = t & 63;
    const int wm = (wave >> 2) * 64;          // 0,64
    const int wn = (wave & 3) * 64;           // 0,64,128,192
    const int l16 = lane & 15, quad = lane >> 4;
    const int srow = t >> 3;                  // staging row 0..63
    const int sch  = (t & 7) ^ (srow & 7);    // swizzled data chunk for this slot

    const u16* Ab = A  + (size_t)(m0 + srow) * C_SZ + sch * 8;
    const u16* Bb = Bw + (size_t)(n0 + srow) * C_SZ + sch * 8;

    f32x4 acc[4][4] = {};

#define STAGE_Ag(b, k0, g) GLL16(Ab + (size_t)(64 * (g)) * C_SZ + (k0), \
                                 &As[b][(g) * 4096 + t * 8])
#define STAGE_Bg(b, k0, g) GLL16(Bb + (size_t)(64 * (g)) * C_SZ + (k0), \
                                 &Bs[b][(g) * 4096 + t * 8])

    // prologue: stage tiles 0 and 1 (6 GLL each, A0,A1,B0..B3 order)
    #pragma unroll
    for (int tb = 0; tb < 2; ++tb) {
        STAGE_Ag(tb, tb * 64, 0); STAGE_Ag(tb, tb * 64, 1);
        STAGE_Bg(tb, tb * 64, 0); STAGE_Bg(tb, tb * 64, 1);
        STAGE_Bg(tb, tb * 64, 2); STAGE_Bg(tb, tb * 64, 3);
    }

    #pragma unroll
    for (int tt = 0; tt < 8; ++tt) {
        const int cb = tt % 3;
        const int nb = (tt + 2) % 3;
        const int k2 = (tt + 2) * 64;
        // counted wait: outstanding = tile tt (6) + tile tt+1 (6); keep tt+1 flying
        if (tt < 7) asm volatile("s_waitcnt vmcnt(6)" ::: "memory");
        else        asm volatile("s_waitcnt vmcnt(0)" ::: "memory");
        __builtin_amdgcn_s_barrier();
        __builtin_amdgcn_sched_barrier(0);

        // ---- phase 0: m-frags 0-1 x all B  (+3 GLL for tile tt+2) ----
        s16x8 af0[2][2], bf[4][2];
        #pragma unroll
        for (int i = 0; i < 2; ++i) {
            const int R = wm + 16 * i + l16;
            af0[i][0] = *(const s16x8*)&As[cb][lds_off(R, quad)];
            af0[i][1] = *(const s16x8*)&As[cb][lds_off(R, 4 + quad)];
        }
        #pragma unroll
        for (int j = 0; j < 4; ++j) {
            const int R = wn + 16 * j + l16;
            bf[j][0] = *(const s16x8*)&Bs[cb][lds_off(R, quad)];
            bf[j][1] = *(const s16x8*)&Bs[cb][lds_off(R, 4 + quad)];
        }
        if (tt < 6) { STAGE_Ag(nb, k2, 0); STAGE_Ag(nb, k2, 1); STAGE_Bg(nb, k2, 0); }
        __builtin_amdgcn_sched_barrier(0);
        __builtin_amdgcn_s_setprio(1);
        #pragma unroll
        for (int i = 0; i < 2; ++i)
            #pragma unroll
            for (int j = 0; j < 4; ++j) {
                acc[i][j] = __builtin_amdgcn_mfma_f32_16x16x32_bf16(af0[i][0], bf[j][0], acc[i][j], 0, 0, 0);
                acc[i][j] = __builtin_amdgcn_mfma_f32_16x16x32_bf16(af0[i][1], bf[j][1], acc[i][j], 0, 0, 0);
            }
        __builtin_amdgcn_s_setprio(0);

        // ---- phase 1: m-frags 2-3 x all B  (+3 GLL for tile tt+2) ----
        s16x8 af1[2][2];
        #pragma unroll
        for (int i = 0; i < 2; ++i) {
            const int R = wm + 32 + 16 * i + l16;
            af1[i][0] = *(const s16x8*)&As[cb][lds_off(R, quad)];
            af1[i][1] = *(const s16x8*)&As[cb][lds_off(R, 4 + quad)];
        }
        if (tt < 6) { STAGE_Bg(nb, k2, 1); STAGE_Bg(nb, k2, 2); STAGE_Bg(nb, k2, 3); }
        __builtin_amdgcn_sched_barrier(0);
        __builtin_amdgcn_s_setprio(1);
        #pragma unroll
        for (int i = 0; i < 2; ++i)
            #pragma unroll
            for (int j = 0; j < 4; ++j) {
                acc[2 + i][j] = __builtin_amdgcn_mfma_f32_16x16x32_bf16(af1[i][0], bf[j][0], acc[2 + i][j], 0, 0, 0);
                acc[2 + i][j] = __builtin_amdgcn_mfma_f32_16x16x32_bf16(af1[i][1], bf[j][1], acc[2 + i][j], 0, 0, 0);
            }
        __builtin_amdgcn_s_setprio(0);
        __builtin_amdgcn_sched_barrier(0);
    }
#undef STAGE_Ag
#undef STAGE_Bg

    // epilogue: C row = m0+wm+16i+quad*4+r, col = n0+wn+16j+l16
    if (MODE == 0) {
        const int bb  = m0 >> 11;                      // batch (block-uniform)
        const int nnb = (m0 & 2047) + wm + (quad << 2);
        if (n0 >= 1024) {
            // pure V block: store transposed [bh][d][n], pack 4 rows -> ushort4
            #pragma unroll
            for (int j = 0; j < 4; ++j) {
                const int c  = n0 - 1024 + wn + 16 * j + l16;   // v col 0..511
                const int h  = c >> 6, dd = c & 63;
                u16* vp = v_ws + (((size_t)bb * NH + h) * HD + dd) * N_SZ + nnb;
                #pragma unroll
                for (int i = 0; i < 4; ++i) {
                    ushort4 st = { f2bf(acc[i][j][0]), f2bf(acc[i][j][1]),
                                   f2bf(acc[i][j][2]), f2bf(acc[i][j][3]) };
                    *(ushort4*)(vp + 16 * i) = st;
                }
            }
        } else {
            u16* T = (n0 < 512) ? q_ws : k_ws;         // block-uniform target
            const int nq = n0 & 511;
            #pragma unroll
            for (int j = 0; j < 4; ++j) {
                const int gn = nq + wn + 16 * j + l16;
                const int h  = (gn >> 6) & 7, dd = gn & 63;
                u16* tp = T + (((size_t)bb * NH + h) * N_SZ + nnb) * HD + dd;
                #pragma unroll
                for (int i = 0; i < 4; ++i)
                    #pragma unroll
                    for (int r = 0; r < 4; ++r)
                        tp[(size_t)(16 * i + r) * HD] = f2bf(acc[i][j][r]);
            }
        }
    } else {
        #pragma unroll
        for (int j = 0; j < 4; ++j) {
            const int gn = n0 + wn + 16 * j + l16;
            const float bv = bias[gn];
            #pragma unroll
            for (int i = 0; i < 4; ++i)
                #pragma unroll
                for (int r = 0; r < 4; ++r)
                    outp[(size_t)(m0 + wm + 16 * i + (quad << 2) + r) * C_SZ + gn]
                        = acc[i][j][r] + bv;
        }
    }
}

// ---------------- MFMA local attention: 2 image rows / block ----------------
// block = (bh, row-pair p): queries = rows 2p,2p+1 (128 q).  Wave w handles the
// 16-query span [16w,16w+16) in BOTH rows, key window [kb,kb+32),
// kb = clamp(16w-8,0,32).  K/V rows 2p-3 .. 2p+4 staged one at a time; V frags
// shared across the two row-subtiles.  Q staged through the K/V LDS then kept in
// registers (26 KB LDS total -> 6 blocks/CU capacity).
__global__ __launch_bounds__(256)
void attn_mfma(const u16* __restrict__ q_ws, const u16* __restrict__ k_ws,
               const u16* __restrict__ vt_ws, u16* __restrict__ o_ws)
{
    __shared__ u16 KV[2][64 * 64];   // [0]=K row, [1]=Vt row; Q staging at start
    __shared__ u16 Ps[4][16 * 40];   // per-wave P, [q16][key32], stride 40 elems

    const int t = threadIdx.x, wave = t >> 6, lane = t & 63;
    const int l16 = lane & 15, quad = lane >> 4;
    const int u  = blockIdx.x;
    const int p  = u & 15;           // row pair
    const int bh = u >> 4;
    const int r0 = 2 * p, r1 = 2 * p + 1;
    const size_t base = (size_t)bh * (N_SZ * HD);
    const int srow = t >> 3;
    const int sch  = (t & 7) ^ (srow & 7);

    // stage Q rows r0,r1 (128x64 = 16 KB) into KV, swizzled; extract frags
    const u16* qg = q_ws + base + (size_t)r0 * (64 * HD);
    u16* Qst = &KV[0][0];
    #pragma unroll
    for (int g = 0; g < 4; ++g)
        GLL16(qg + (size_t)(srow + 32 * g) * 64 + sch * 8, Qst + g * 2048 + t * 8);
    __syncthreads();

    s16x8 aQ[2][2];
    #pragma unroll
    for (int s = 0; s < 2; ++s) {
        const int Rq = 64 * s + 16 * wave + l16;
        aQ[s][0] = *(const s16x8*)&Qst[lds_off(Rq, quad)];
        aQ[s][1] = *(const s16x8*)&Qst[lds_off(Rq, 4 + quad)];
    }

    const int kb = min(max(16 * wave - 8, 0), 32);   // 0, 8, 24, 32

    f32x4 accO[2][4] = {};
    float lp[2][4] = {};

    const int hlo = (r0 - 3 < 0) ? 0 : r0 - 3;
    const int hhi = (r1 + 3 > H_SZ - 1) ? H_SZ - 1 : r1 + 3;

    for (int hh = hlo; hh <= hhi; ++hh) {
        __syncthreads();   // previous iter's reads (and Q extract) done
        const u16* kg = k_ws + base + (size_t)hh * (64 * HD);
        GLL16(kg + (size_t)srow        * 64 + sch * 8, &KV[0][t * 8]);
        GLL16(kg + (size_t)(srow + 32) * 64 + sch * 8, &KV[0][2048 + t * 8]);
        const u16* vg = vt_ws + base + (size_t)hh * 64;
        GLL16(vg + (size_t)srow        * N_SZ + sch * 8, &KV[1][t * 8]);
        GLL16(vg + (size_t)(srow + 32) * N_SZ + sch * 8, &KV[1][2048 + t * 8]);
        __syncthreads();

        // K/V frags for this wave's 32-key window
        s16x8 bK[2][2];
        #pragma unroll
        for (int j = 0; j < 2; ++j) {
            const int Rk = kb + 16 * j + l16;
            bK[j][0] = *(const s16x8*)&KV[0][lds_off(Rk, quad)];
            bK[j][1] = *(const s16x8*)&KV[0][lds_off(Rk, 4 + quad)];
        }
        s16x8 vf[4];
        #pragma unroll
        for (int j = 0; j < 4; ++j)
            vf[j] = *(const s16x8*)&KV[1][lds_off(16 * j + l16, (kb >> 3) + quad)];

        #pragma unroll
        for (int s = 0; s < 2; ++s) {
            const int dh = hh - (r0 + s);
            if (dh * dh > 9) continue;     // wave-uniform: row out of +-3 range
            f32x4 z[2] = {{0.f,0.f,0.f,0.f},{0.f,0.f,0.f,0.f}};
            #pragma unroll
            for (int j = 0; j < 2; ++j) {
                z[j] = __builtin_amdgcn_mfma_f32_16x16x32_bf16(aQ[s][0], bK[j][0], z[j], 0, 0, 0);
                z[j] = __builtin_amdgcn_mfma_f32_16x16x32_bf16(aQ[s][1], bK[j][1], z[j], 0, 0, 0);
            }
            #pragma unroll
            for (int j = 0; j < 2; ++j) {
                const int ww = kb + 16 * j + l16;   // key w-coord
                #pragma unroll
                for (int r = 0; r < 4; ++r) {
                    const int dw = ww - (16 * wave + quad * 4 + r);
                    const float pv = (dw * dw <= 25) ? __expf(z[j][r]) : 0.f;
                    const u16 pb = f2bf(pv);
                    lp[s][r] += bf2f(pb);
                    Ps[wave][(quad * 4 + r) * 40 + 16 * j + l16] = pb;
                }
            }
            s16x8 aP = *(const s16x8*)&Ps[wave][l16 * 40 + quad * 8];
            #pragma unroll
            for (int j = 0; j < 4; ++j)
                accO[s][j] = __builtin_amdgcn_mfma_f32_16x16x32_bf16(aP, vf[j], accO[s][j], 0, 0, 0);
        }
    }

    // reduce l across the 16 lanes sharing a quad-row (disjoint key subsets)
    #pragma unroll
    for (int s = 0; s < 2; ++s)
        #pragma unroll
        for (int r = 0; r < 4; ++r) {
            lp[s][r] += __shfl_xor(lp[s][r], 1);
            lp[s][r] += __shfl_xor(lp[s][r], 2);
            lp[s][r] += __shfl_xor(lp[s][r], 4);
            lp[s][r] += __shfl_xor(lp[s][r], 8);
        }

    // write O in (B, N, C) layout for the proj GEMM
    const int bb = bh >> 3, h = bh & 7;
    #pragma unroll
    for (int s = 0; s < 2; ++s)
        #pragma unroll
        for (int j = 0; j < 4; ++j)
            #pragma unroll
            for (int r = 0; r < 4; ++r) {
                const int row = (r0 + s) * 64 + 16 * wave + quad * 4 + r;
                o_ws[((size_t)bb * N_SZ + row) * C_SZ + h * 64 + 16 * j + l16]
                    = f2bf(accO[s][j][r] / lp[s][r]);
            }
}

extern "C" void kernel_launch(void* const* d_in, const int* in_sizes, int n_in,
                              void* d_out, int out_size, void* d_ws, size_t ws_size,
                              hipStream_t stream)
{
    const float* x      = (const float*)d_in[0];
    const float* qkv_w  = (const float*)d_in[1];
    const float* proj_w = (const float*)d_in[2];
    const float* proj_b = (const float*)d_in[3];
    float* outp = (float*)d_out;

    const size_t seg = (size_t)B_SZ * NH * N_SZ * HD;  // 8388608 elems
    u16* q_ws = (u16*)d_ws;
    u16* k_ws = q_ws + seg;
    u16* v_ws = k_ws + seg;      // transposed layout [bh][d][n]
    u16* o_ws = v_ws + seg;
    u16* xb   = o_ws + seg;                       // x as bf16 (8.4M elems)
    u16* qwb  = xb + (size_t)16384 * 512;         // qkv_w bf16 (786432)
    u16* pwb  = qwb + (size_t)1536 * 512;         // proj_w bf16 (262144)

    // one fused convert: (NX4+NQ4+NP4)/256 = 9216 blocks
    conv_all<<<9216, 256, 0, stream>>>(x, qkv_w, proj_w, xb, qwb, pwb);

    // QKV GEMM: M=16384, N=1536, K=512 -> 128 x 6 = 768 blocks (3 exact rounds)
    gemm8<0, 6><<<768, 512, 0, stream>>>(xb, qwb, nullptr,
                                         q_ws, k_ws, v_ws, nullptr);
    // local attention, one block per (b,h,row-pair)
    attn_mfma<<<B_SZ * NH * (H_SZ / 2), 256, 0, stream>>>(q_ws, k_ws, v_ws, o_ws);
    // proj GEMM: M=16384, N=512, K=512 (+bias, fp32 out) -> 128 x 2 = 256 blocks
    gemm8<1, 2><<<256, 512, 0, stream>>>(o_ws, pwb, proj_b,
                                         nullptr, nullptr, nullptr, outp);
}